// Round 6
// baseline (342.294 us; speedup 1.0000x reference)
//
#include <hip/hip_runtime.h>

// ShallowRBF: x(8192x2048), centers(4096x2048), beta(4096), W(1000x4096), b(1000)
// out = (exp(-beta*||x-c||) @ W^T) / rowsum + b
//
// R9: (1) 1 barrier/tile: ALL staging (A+B of t+1) targets the OTHER buffer,
// issued at ph0; no wave ever writes a buffer being read -> mid-tile barrier
// gone. vmcnt(0) at tile end is a free drain (issued ~2400cyc earlier).
// (2) quarter-pipelined LDS reads: af0/af1 double-buffer, READ_A(q+1) issued
// before MFMA_Q(q) -> lgkmcnt(0) waits on ~310cyc-old reads (latency hidden).
// Carried: chunk^(row&7) swizzle (0 conflicts), LDS rowsum partials,
// psum[16][8192] in dead out buf, gemm2 XCD remap.

#define BB 8192
#define DD 2048
#define CC 4096
#define KK 1000
#define KP 1024

typedef unsigned short u16;
typedef __bf16 bf16x8 __attribute__((ext_vector_type(8)));
typedef float f32x4 __attribute__((ext_vector_type(4)));

typedef const void __attribute__((address_space(1)))* gvp_t;
typedef void __attribute__((address_space(3)))* lvp_t;

__device__ __forceinline__ u16 f2bf(float f) {
  union { float f; unsigned u; } v; v.f = f;
  return (u16)((v.u + 0x7fffu + ((v.u >> 16) & 1u)) >> 16);  // RNE
}

// ---- prep (fused): row norms + bf16 casts of x, centers; W cast+pad ----
__global__ void prep_all(const float* __restrict__ x, const float* __restrict__ cen,
                         const float* __restrict__ W,
                         u16* __restrict__ xb, u16* __restrict__ cb,
                         u16* __restrict__ wb,
                         float* __restrict__ x2, float* __restrict__ c2) {
  int row = blockIdx.x;
  int t = threadIdx.x;
  if (row >= BB + CC) {  // W rows (padded to KP with zeros)
    int r = row - BB - CC;
    ushort4* dst = reinterpret_cast<ushort4*>(wb + (size_t)r * CC);
    if (r < KK) {
      const float4* src = reinterpret_cast<const float4*>(W + (size_t)r * CC);
#pragma unroll
      for (int m = 0; m < 4; ++m) {
        float4 v = src[t + 256 * m];
        dst[t + 256 * m] = make_ushort4(f2bf(v.x), f2bf(v.y), f2bf(v.z), f2bf(v.w));
      }
    } else {
#pragma unroll
      for (int m = 0; m < 4; ++m) dst[t + 256 * m] = make_ushort4(0, 0, 0, 0);
    }
    return;
  }
  const float* src;
  u16* dst;
  float* nrm;
  if (row < BB) {
    src = x + (size_t)row * DD; dst = xb + (size_t)row * DD; nrm = x2 + row;
  } else {
    int r = row - BB;
    src = cen + (size_t)r * DD; dst = cb + (size_t)r * DD; nrm = c2 + r;
  }
  float s = 0.f;
#pragma unroll
  for (int m = 0; m < 2; ++m) {
    int idx = t + 256 * m;
    float4 v = reinterpret_cast<const float4*>(src)[idx];
    s += v.x * v.x + v.y * v.y + v.z * v.z + v.w * v.w;
    reinterpret_cast<ushort4*>(dst)[idx] =
        make_ushort4(f2bf(v.x), f2bf(v.y), f2bf(v.z), f2bf(v.w));
  }
#pragma unroll
  for (int off = 1; off < 64; off <<= 1) s += __shfl_xor(s, off);
  __shared__ float red[4];
  if ((t & 63) == 0) red[t >> 6] = s;
  __syncthreads();
  if (t == 0) *nrm = red[0] + red[1] + red[2] + red[3];
}

// ======================= shared schedule helpers =======================
#define SB0 __builtin_amdgcn_sched_barrier(0)
#define BARR __builtin_amdgcn_s_barrier()
#define LGKM0 asm volatile("s_waitcnt lgkmcnt(0)" ::: "memory")
#define VM0 asm volatile("s_waitcnt vmcnt(0)" ::: "memory")

// ======================= GEMM1: 256x256, 1 barrier/tile =======================
// LDS/buffer (64KB): A 256x64 bf16 @0, B 256x64 @32768. Row=128B; logical
// chunk s of row r at phys chunk s^(r&7). Linear gload_lds dest +
// pre-swizzled global source.

#define ST_A(BUF, H, TILE)                                                         \
  {                                                                                \
    const u16* _s = gA0 + (size_t)((H) * 128) * DD + (TILE) * 64;                  \
    char* _d = (char*)smem + (BUF) * 65536 + (H) * 16384 + t * 16;                 \
    __builtin_amdgcn_global_load_lds((gvp_t)_s, (lvp_t)_d, 16, 0, 0);              \
    __builtin_amdgcn_global_load_lds((gvp_t)(_s + (size_t)64 * DD),                \
                                     (lvp_t)(_d + 8192), 16, 0, 0);                \
  }

#define ST_B(BUF, H, TILE)                                                         \
  {                                                                                \
    const u16* _s = gB0 + (size_t)((H) * 128) * DD + (TILE) * 64;                  \
    char* _d = (char*)smem + (BUF) * 65536 + 32768 + (H) * 16384 + t * 16;         \
    __builtin_amdgcn_global_load_lds((gvp_t)_s, (lvp_t)_d, 16, 0, 0);              \
    __builtin_amdgcn_global_load_lds((gvp_t)(_s + (size_t)64 * DD),                \
                                     (lvp_t)(_d + 8192), 16, 0, 0);                \
  }

#define READ_B(SBP)                                                                \
  _Pragma("unroll") for (int n_ = 0; n_ < 4; ++n_) {                               \
    _Pragma("unroll") for (int ks_ = 0; ks_ < 2; ++ks_) {                          \
      bfr[n_][ks_] = *(const bf16x8*)((SBP) + bRow + n_ * 2048 + cbv[ks_]);        \
    }                                                                              \
  }

#define READ_AF(DST, SAP, MQ)                                                      \
  _Pragma("unroll") for (int m_ = 0; m_ < 2; ++m_) {                               \
    _Pragma("unroll") for (int ks_ = 0; ks_ < 2; ++ks_) {                          \
      DST[m_][ks_] =                                                               \
          *(const bf16x8*)((SAP) + aRow + ((MQ)*2 + m_) * 2048 + cbv[ks_]);        \
    }                                                                              \
  }

#define MFMA_QF(SRC, MQ)                                                           \
  __builtin_amdgcn_s_setprio(1);                                                   \
  _Pragma("unroll") for (int m_ = 0; m_ < 2; ++m_) {                               \
    _Pragma("unroll") for (int n_ = 0; n_ < 4; ++n_) {                             \
      _Pragma("unroll") for (int ks_ = 0; ks_ < 2; ++ks_) {                        \
        acc[(MQ)*2 + m_][n_] = __builtin_amdgcn_mfma_f32_16x16x32_bf16(            \
            SRC[m_][ks_], bfr[n_][ks_], acc[(MQ)*2 + m_][n_], 0, 0, 0);            \
      }                                                                            \
    }                                                                              \
  }                                                                                \
  __builtin_amdgcn_s_setprio(0)

// 1 barrier/tile: all stages -> buffer 1-CUR (no wave reads it this tile);
// vmcnt(0) at tile end drains loads issued at ph0 (free). Quarter reads
// pipelined via af0/af1: lgkmcnt(0) always waits on reads issued one MFMA
// cluster (~310cyc) earlier.
#define TILE_BODY(TILE, CUR, DOS)                                                  \
  {                                                                                \
    const char* sA_ = (const char*)smem + (CUR) * 65536;                           \
    const char* sB_ = sA_ + 32768;                                                 \
    READ_B(sB_);                                                                   \
    READ_AF(af0, sA_, 0);                                                          \
    SB0;                                                                           \
    if (DOS) {                                                                     \
      ST_A(1 - (CUR), 0, (TILE) + 1); ST_A(1 - (CUR), 1, (TILE) + 1);              \
      ST_B(1 - (CUR), 0, (TILE) + 1); ST_B(1 - (CUR), 1, (TILE) + 1);              \
    }                                                                              \
    SB0; LGKM0; SB0;                                                               \
    READ_AF(af1, sA_, 1); SB0;                                                     \
    MFMA_QF(af0, 0); SB0; LGKM0; SB0;                                              \
    READ_AF(af0, sA_, 2); SB0;                                                     \
    MFMA_QF(af1, 1); SB0; LGKM0; SB0;                                              \
    READ_AF(af1, sA_, 3); SB0;                                                     \
    MFMA_QF(af0, 2); SB0; LGKM0; SB0;                                              \
    MFMA_QF(af1, 3);                                                               \
    if (DOS) { VM0; }                                                              \
    SB0; BARR;                                                                     \
  }

__global__ __launch_bounds__(512, 2)
void gemm1_rbf(const u16* __restrict__ Abf, const u16* __restrict__ Bbf,
               const float* __restrict__ x2, const float* __restrict__ c2,
               const float* __restrict__ beta, u16* __restrict__ Ebf,
               float* __restrict__ psum) {
  constexpr int NT = DD / 64;  // 32 K-tiles
  __shared__ __align__(16) char smem[131072];

  const int t = threadIdx.x;
  const int lane = t & 63;
  const int wave = t >> 6;
  const int wr = wave >> 2;  // 0..1: rows wr*128..
  const int wc = wave & 3;   // 0..3: cols wc*64..
  const int l15 = lane & 15;

  const int rowBase = blockIdx.y * 256;
  const int colBase = blockIdx.x * 256;

  f32x4 acc[8][4];
#pragma unroll
  for (int i = 0; i < 8; ++i)
#pragma unroll
    for (int j = 0; j < 4; ++j) acc[i][j] = 0.f;

  // staging source (pre-swizzled logical chunk)
  const int srow = t >> 3;
  const u16* gA0 = Abf + (size_t)(rowBase + srow) * DD + ((t & 7) ^ (srow & 7)) * 8;
  const u16* gB0 = Bbf + (size_t)(colBase + srow) * DD + ((t & 7) ^ (srow & 7)) * 8;

  // frag-read byte column per kstep: phys chunk = (ks*4 + l>>4) ^ (l&7)
  int cbv[2];
  cbv[0] = (((lane >> 4) & 3) ^ (lane & 7)) << 4;
  cbv[1] = ((4 + ((lane >> 4) & 3)) ^ (lane & 7)) << 4;
  const int aRow = (wr * 128 + l15) * 128;
  const int bRow = (wc * 64 + l15) * 128;

  bf16x8 bfr[4][2];
  bf16x8 af0[2][2], af1[2][2];

  // prologue: stage tile0 into buf0
  ST_A(0, 0, 0); ST_A(0, 1, 0); ST_B(0, 0, 0); ST_B(0, 1, 0);
  VM0;
  BARR;

#pragma unroll 2
  for (int tile = 0; tile < NT - 1; ++tile) {
    TILE_BODY(tile, tile & 1, true);
  }
  TILE_BODY(NT - 1, (NT - 1) & 1, false);

  // epilogue: C/D layout (16x16): col = lane&15, row = (lane>>4)*4 + reg
  const int khi4 = (lane >> 4) * 4;
  float* lrs = (float*)smem;  // [256 rows][stride 68] f32 partials
  float c2v[4], bet[4];
  int gc[4];
#pragma unroll
  for (int n = 0; n < 4; ++n) {
    gc[n] = colBase + wc * 64 + n * 16 + l15;
    c2v[n] = c2[gc[n]];
    bet[n] = beta[gc[n]];
  }
#pragma unroll
  for (int m = 0; m < 8; ++m) {
#pragma unroll
    for (int r = 0; r < 4; ++r) {
      const int rrel = wr * 128 + m * 16 + khi4 + r;
      const int grow = rowBase + rrel;
      const float x2v = x2[grow];
      u16* orow = Ebf + (size_t)grow * CC;
      float rs = 0.f;
#pragma unroll
      for (int n = 0; n < 4; ++n) {
        float d = acc[m][n][r];
        float sq = fmaxf(x2v + c2v[n] - 2.0f * d, 0.0f);
        float e = __expf(-bet[n] * __builtin_amdgcn_sqrtf(sq));
        rs += e;
        orow[gc[n]] = f2bf(e);
      }
      lrs[rrel * 68 + wc * 16 + l15] = rs;  // conflict-free (stride-68 pad)
    }
  }
  __syncthreads();
  if (t < 256) {
    const f32x4* p = (const f32x4*)(lrs + t * 68);  // 272B stride, 16B-aligned
    float s = 0.f;
#pragma unroll
    for (int i = 0; i < 16; ++i) {
      f32x4 v = p[i];
      s += v[0] + v[1] + v[2] + v[3];
    }
    psum[(size_t)blockIdx.x * BB + rowBase + t] = s;  // coalesced
  }
}

// ---- rowsum reduce: rowsum[r] = sum_b psum[b][r]  (psum is [16][8192]) ----
__global__ void rowsum_reduce(const float* __restrict__ psum, float* __restrict__ rowsum) {
  const int row = blockIdx.x * 256 + threadIdx.x;
  float s = 0.f;
#pragma unroll
  for (int b = 0; b < 16; ++b) s += psum[(size_t)b * BB + row];
  rowsum[row] = s;
}

// ============ GEMM2: 256x128, 1 barrier/tile; out = (E @ W^T)/rowsum + b ============
// LDS/buffer (48KB): A 256x64 bf16 (32KB) @0, B 128x64 (16KB) @32768.
// All staging (A+B of t+1) -> other buffer at ph0; vmcnt(0) at tile end.
// XCD-aware remap: co-locate the 8 col-blocks of one E-band per XCD.

#define ST2_A(BUF, H, TILE)                                                        \
  {                                                                                \
    const u16* _s = gA0 + (size_t)((H) * 128) * CC + (TILE) * 64;                  \
    char* _d = (char*)smem + (BUF) * 49152 + (H) * 16384 + t * 16;                 \
    __builtin_amdgcn_global_load_lds((gvp_t)_s, (lvp_t)_d, 16, 0, 0);              \
    __builtin_amdgcn_global_load_lds((gvp_t)(_s + (size_t)64 * CC),                \
                                     (lvp_t)(_d + 8192), 16, 0, 0);                \
  }

#define ST2_B(BUF, TILE)                                                           \
  {                                                                                \
    const u16* _s = gB0 + (TILE) * 64;                                             \
    char* _d = (char*)smem + (BUF) * 49152 + 32768 + t * 16;                       \
    __builtin_amdgcn_global_load_lds((gvp_t)_s, (lvp_t)_d, 16, 0, 0);              \
    __builtin_amdgcn_global_load_lds((gvp_t)(_s + (size_t)64 * CC),                \
                                     (lvp_t)(_d + 8192), 16, 0, 0);                \
  }

#define READ2_B(SBP)                                                               \
  _Pragma("unroll") for (int n_ = 0; n_ < 2; ++n_) {                               \
    _Pragma("unroll") for (int ks_ = 0; ks_ < 2; ++ks_) {                          \
      bfr[n_][ks_] = *(const bf16x8*)((SBP) + bRow + n_ * 2048 + cbv[ks_]);        \
    }                                                                              \
  }

#define READ2_AF(DST, SAP, MQ)                                                     \
  _Pragma("unroll") for (int m_ = 0; m_ < 2; ++m_) {                               \
    _Pragma("unroll") for (int ks_ = 0; ks_ < 2; ++ks_) {                          \
      DST[m_][ks_] =                                                               \
          *(const bf16x8*)((SAP) + aRow + ((MQ)*2 + m_) * 2048 + cbv[ks_]);        \
    }                                                                              \
  }

#define MFMA2_QF(SRC, MQ)                                                          \
  __builtin_amdgcn_s_setprio(1);                                                   \
  _Pragma("unroll") for (int m_ = 0; m_ < 2; ++m_) {                               \
    _Pragma("unroll") for (int n_ = 0; n_ < 2; ++n_) {                             \
      _Pragma("unroll") for (int ks_ = 0; ks_ < 2; ++ks_) {                        \
        acc[(MQ)*2 + m_][n_] = __builtin_amdgcn_mfma_f32_16x16x32_bf16(            \
            SRC[m_][ks_], bfr[n_][ks_], acc[(MQ)*2 + m_][n_], 0, 0, 0);            \
      }                                                                            \
    }                                                                              \
  }                                                                                \
  __builtin_amdgcn_s_setprio(0)

#define TILE2_BODY(TILE, CUR, DOS)                                                 \
  {                                                                                \
    const char* sA_ = (const char*)smem + (CUR) * 49152;                           \
    const char* sB_ = sA_ + 32768;                                                 \
    READ2_B(sB_);                                                                  \
    READ2_AF(af0, sA_, 0);                                                         \
    SB0;                                                                           \
    if (DOS) {                                                                     \
      ST2_A(1 - (CUR), 0, (TILE) + 1); ST2_A(1 - (CUR), 1, (TILE) + 1);            \
      ST2_B(1 - (CUR), (TILE) + 1);                                                \
    }                                                                              \
    SB0; LGKM0; SB0;                                                               \
    READ2_AF(af1, sA_, 1); SB0;                                                    \
    MFMA2_QF(af0, 0); SB0; LGKM0; SB0;                                             \
    READ2_AF(af0, sA_, 2); SB0;                                                    \
    MFMA2_QF(af1, 1); SB0; LGKM0; SB0;                                             \
    READ2_AF(af1, sA_, 3); SB0;                                                    \
    MFMA2_QF(af0, 2); SB0; LGKM0; SB0;                                             \
    MFMA2_QF(af1, 3);                                                              \
    if (DOS) { VM0; }                                                              \
    SB0; BARR;                                                                     \
  }

__global__ __launch_bounds__(512, 2)
void gemm2_out(const u16* __restrict__ Ebf, const u16* __restrict__ Wbf,
               const float* __restrict__ rowsum, const float* __restrict__ bias,
               float* __restrict__ out) {
  constexpr int NT = CC / 64;  // 64 K-tiles
  __shared__ __align__(16) char smem[98304];

  const int t = threadIdx.x;
  const int lane = t & 63;
  const int wave = t >> 6;
  const int wr = wave >> 2;  // 0..1: rows wr*128..
  const int wc = wave & 3;   // 0..3: cols wc*32..
  const int l15 = lane & 15;

  // XCD-aware remap (bijective on 256 blocks): dispatch d -> XCD d%8.
  const int d = blockIdx.x + (blockIdx.y << 3);
  const int s_ = d >> 3;
  const int by = (d & 7) + ((s_ >> 3) << 3);
  const int bx = s_ & 7;

  const int rowBase = by * 256;
  const int colBase = bx * 128;

  f32x4 acc[8][2];
#pragma unroll
  for (int i = 0; i < 8; ++i)
#pragma unroll
    for (int j = 0; j < 2; ++j) acc[i][j] = 0.f;

  const int srow = t >> 3;
  const u16* gA0 = Ebf + (size_t)(rowBase + srow) * CC + ((t & 7) ^ (srow & 7)) * 8;
  const u16* gB0 = Wbf + (size_t)(colBase + srow) * CC + ((t & 7) ^ (srow & 7)) * 8;

  int cbv[2];
  cbv[0] = (((lane >> 4) & 3) ^ (lane & 7)) << 4;
  cbv[1] = ((4 + ((lane >> 4) & 3)) ^ (lane & 7)) << 4;
  const int aRow = (wr * 128 + l15) * 128;
  const int bRow = (wc * 32 + l15) * 128;

  bf16x8 bfr[2][2];
  bf16x8 af0[2][2], af1[2][2];

  // prologue: stage tile0 into buf0
  ST2_A(0, 0, 0); ST2_A(0, 1, 0); ST2_B(0, 0);
  VM0;
  BARR;

#pragma unroll 2
  for (int tile = 0; tile < NT - 1; ++tile) {
    TILE2_BODY(tile, tile & 1, true);
  }
  TILE2_BODY(NT - 1, (NT - 1) & 1, false);

  // epilogue
  const int khi4 = (lane >> 4) * 4;
  int gc[2];
  float bv[2];
#pragma unroll
  for (int n = 0; n < 2; ++n) {
    gc[n] = colBase + wc * 32 + n * 16 + l15;
    bv[n] = (gc[n] < KK) ? bias[gc[n]] : 0.f;
  }
#pragma unroll
  for (int m = 0; m < 8; ++m) {
#pragma unroll
    for (int r = 0; r < 4; ++r) {
      const int grow = rowBase + wr * 128 + m * 16 + khi4 + r;
      const float inv = 1.0f / rowsum[grow];
#pragma unroll
      for (int n = 0; n < 2; ++n) {
        if (gc[n] < KK)
          out[(size_t)grow * KK + gc[n]] = acc[m][n][r] * inv + bv[n];
      }
    }
  }
}

// ---- workspace layout (bytes) ----
#define OFF_XB 0u                    // 8192*2048*2 = 33554432
#define OFF_CB 33554432u             // 4096*2048*2 = 16777216
#define OFF_WB 50331648u             // 1024*4096*2 = 8388608
#define OFF_EB 58720256u             // 8192*4096*2 = 67108864
#define OFF_X2 125829120u            // 8192*4
#define OFF_C2 125861888u            // 4096*4
#define OFF_RS 125878272u            // 8192*4

extern "C" void kernel_launch(void* const* d_in, const int* in_sizes, int n_in,
                              void* d_out, int out_size, void* d_ws, size_t ws_size,
                              hipStream_t stream) {
  const float* x = (const float*)d_in[0];
  const float* cen = (const float*)d_in[1];
  const float* beta = (const float*)d_in[2];
  const float* W = (const float*)d_in[3];
  const float* bias = (const float*)d_in[4];
  float* out = (float*)d_out;
  char* ws = (char*)d_ws;

  u16* xb = (u16*)(ws + OFF_XB);
  u16* cb = (u16*)(ws + OFF_CB);
  u16* wb = (u16*)(ws + OFF_WB);
  u16* eb = (u16*)(ws + OFF_EB);
  float* x2 = (float*)(ws + OFF_X2);
  float* c2 = (float*)(ws + OFF_C2);
  float* rowsum = (float*)(ws + OFF_RS);
  float* psum = out;  // [16][8192] f32 = 512KB scratch in the (dead until gemm2) out buffer

  prep_all<<<BB + CC + KP, 256, 0, stream>>>(x, cen, W, xb, cb, wb, x2, c2);
  gemm1_rbf<<<dim3(CC / 256, BB / 256), 512, 0, stream>>>(xb, cb, x2, c2, beta, eb, psum);
  rowsum_reduce<<<BB / 256, 256, 0, stream>>>(psum, rowsum);
  gemm2_out<<<dim3(KP / 128, BB / 256), 512, 0, stream>>>(eb, wb, rowsum, bias, out);
}

// Round 7
// 341.397 us; speedup vs baseline: 1.0026x; 1.0026x over previous
//
#include <hip/hip_runtime.h>

// ShallowRBF: x(8192x2048), centers(4096x2048), beta(4096), W(1000x4096), b(1000)
// out = (exp(-beta*||x-c||) @ W^T) / rowsum + b
//
// R10: (1) gemm1: 2-deep counted-lgkmcnt(8) quarter pipeline - LDS queue
// always holds >=8 reads to drain DURING the MFMA cluster (R9's lgkmcnt(0)
// drained everything -> serialization at 2 waves/SIMD). (2) gemm2 reverted
// to R8's measured-best schedule (2 barriers, counted vmcnt(2), B staged
// 2 tiles ahead). (3) rowsum_reduce fused into gemm2 prologue (psum summed
// into rsum_lds[256] under the existing staging vmcnt+barrier).

#define BB 8192
#define DD 2048
#define CC 4096
#define KK 1000
#define KP 1024

typedef unsigned short u16;
typedef __bf16 bf16x8 __attribute__((ext_vector_type(8)));
typedef float f32x4 __attribute__((ext_vector_type(4)));

typedef const void __attribute__((address_space(1)))* gvp_t;
typedef void __attribute__((address_space(3)))* lvp_t;

__device__ __forceinline__ u16 f2bf(float f) {
  union { float f; unsigned u; } v; v.f = f;
  return (u16)((v.u + 0x7fffu + ((v.u >> 16) & 1u)) >> 16);  // RNE
}

// ---- prep (fused): row norms + bf16 casts of x, centers; W cast+pad ----
__global__ void prep_all(const float* __restrict__ x, const float* __restrict__ cen,
                         const float* __restrict__ W,
                         u16* __restrict__ xb, u16* __restrict__ cb,
                         u16* __restrict__ wb,
                         float* __restrict__ x2, float* __restrict__ c2) {
  int row = blockIdx.x;
  int t = threadIdx.x;
  if (row >= BB + CC) {  // W rows (padded to KP with zeros)
    int r = row - BB - CC;
    ushort4* dst = reinterpret_cast<ushort4*>(wb + (size_t)r * CC);
    if (r < KK) {
      const float4* src = reinterpret_cast<const float4*>(W + (size_t)r * CC);
#pragma unroll
      for (int m = 0; m < 4; ++m) {
        float4 v = src[t + 256 * m];
        dst[t + 256 * m] = make_ushort4(f2bf(v.x), f2bf(v.y), f2bf(v.z), f2bf(v.w));
      }
    } else {
#pragma unroll
      for (int m = 0; m < 4; ++m) dst[t + 256 * m] = make_ushort4(0, 0, 0, 0);
    }
    return;
  }
  const float* src;
  u16* dst;
  float* nrm;
  if (row < BB) {
    src = x + (size_t)row * DD; dst = xb + (size_t)row * DD; nrm = x2 + row;
  } else {
    int r = row - BB;
    src = cen + (size_t)r * DD; dst = cb + (size_t)r * DD; nrm = c2 + r;
  }
  float s = 0.f;
#pragma unroll
  for (int m = 0; m < 2; ++m) {
    int idx = t + 256 * m;
    float4 v = reinterpret_cast<const float4*>(src)[idx];
    s += v.x * v.x + v.y * v.y + v.z * v.z + v.w * v.w;
    reinterpret_cast<ushort4*>(dst)[idx] =
        make_ushort4(f2bf(v.x), f2bf(v.y), f2bf(v.z), f2bf(v.w));
  }
#pragma unroll
  for (int off = 1; off < 64; off <<= 1) s += __shfl_xor(s, off);
  __shared__ float red[4];
  if ((t & 63) == 0) red[t >> 6] = s;
  __syncthreads();
  if (t == 0) *nrm = red[0] + red[1] + red[2] + red[3];
}

// ======================= shared schedule helpers =======================
#define SB0 __builtin_amdgcn_sched_barrier(0)
#define BARR __builtin_amdgcn_s_barrier()
#define LGKM0 asm volatile("s_waitcnt lgkmcnt(0)" ::: "memory")
#define LGKM8 asm volatile("s_waitcnt lgkmcnt(8)" ::: "memory")
#define VM0 asm volatile("s_waitcnt vmcnt(0)" ::: "memory")

// ======================= GEMM1: 256x256, 1 barrier/tile =======================
// LDS/buffer (64KB): A 256x64 bf16 @0, B 256x64 @32768. Row=128B; logical
// chunk s of row r at phys chunk s^(r&7). Linear gload_lds dest +
// pre-swizzled global source.

#define ST_A(BUF, H, TILE)                                                         \
  {                                                                                \
    const u16* _s = gA0 + (size_t)((H) * 128) * DD + (TILE) * 64;                  \
    char* _d = (char*)smem + (BUF) * 65536 + (H) * 16384 + t * 16;                 \
    __builtin_amdgcn_global_load_lds((gvp_t)_s, (lvp_t)_d, 16, 0, 0);              \
    __builtin_amdgcn_global_load_lds((gvp_t)(_s + (size_t)64 * DD),                \
                                     (lvp_t)(_d + 8192), 16, 0, 0);                \
  }

#define ST_B(BUF, H, TILE)                                                         \
  {                                                                                \
    const u16* _s = gB0 + (size_t)((H) * 128) * DD + (TILE) * 64;                  \
    char* _d = (char*)smem + (BUF) * 65536 + 32768 + (H) * 16384 + t * 16;         \
    __builtin_amdgcn_global_load_lds((gvp_t)_s, (lvp_t)_d, 16, 0, 0);              \
    __builtin_amdgcn_global_load_lds((gvp_t)(_s + (size_t)64 * DD),                \
                                     (lvp_t)(_d + 8192), 16, 0, 0);                \
  }

#define READ_B(SBP)                                                                \
  _Pragma("unroll") for (int n_ = 0; n_ < 4; ++n_) {                               \
    _Pragma("unroll") for (int ks_ = 0; ks_ < 2; ++ks_) {                          \
      bfr[n_][ks_] = *(const bf16x8*)((SBP) + bRow + n_ * 2048 + cbv[ks_]);        \
    }                                                                              \
  }

#define READ_AF(DST, SAP, MQ)                                                      \
  _Pragma("unroll") for (int m_ = 0; m_ < 2; ++m_) {                               \
    _Pragma("unroll") for (int ks_ = 0; ks_ < 2; ++ks_) {                          \
      DST[m_][ks_] =                                                               \
          *(const bf16x8*)((SAP) + aRow + ((MQ)*2 + m_) * 2048 + cbv[ks_]);        \
    }                                                                              \
  }

#define MFMA_QF(SRC, MQ)                                                           \
  __builtin_amdgcn_s_setprio(1);                                                   \
  _Pragma("unroll") for (int m_ = 0; m_ < 2; ++m_) {                               \
    _Pragma("unroll") for (int n_ = 0; n_ < 4; ++n_) {                             \
      _Pragma("unroll") for (int ks_ = 0; ks_ < 2; ++ks_) {                        \
        acc[(MQ)*2 + m_][n_] = __builtin_amdgcn_mfma_f32_16x16x32_bf16(            \
            SRC[m_][ks_], bfr[n_][ks_], acc[(MQ)*2 + m_][n_], 0, 0, 0);            \
      }                                                                            \
    }                                                                              \
  }                                                                                \
  __builtin_amdgcn_s_setprio(0)

// 2-deep quarter pipeline: issue B+A0+A1 at tile start; before each MFMA
// cluster wait lgkmcnt(8) (next quarter's 8 reads stay in flight); issue
// quarter q+2 before cluster q. LDS queue drains DURING MFMA.
// 1 barrier/tile: all staging -> other buffer; vmcnt(0) drain at tile end
// (issued ~2400cyc earlier).
#define TILE_BODY(TILE, CUR, DOS)                                                  \
  {                                                                                \
    const char* sA_ = (const char*)smem + (CUR) * 65536;                           \
    const char* sB_ = sA_ + 32768;                                                 \
    READ_B(sB_);                                                                   \
    READ_AF(af0, sA_, 0);                                                          \
    READ_AF(af1, sA_, 1);                                                          \
    SB0;                                                                           \
    if (DOS) {                                                                     \
      ST_A(1 - (CUR), 0, (TILE) + 1); ST_A(1 - (CUR), 1, (TILE) + 1);              \
      ST_B(1 - (CUR), 0, (TILE) + 1); ST_B(1 - (CUR), 1, (TILE) + 1);              \
    }                                                                              \
    SB0; LGKM8; SB0;          /* B+af0 ready; af1 in flight */                     \
    READ_AF(af2, sA_, 2); SB0;                                                     \
    MFMA_QF(af0, 0); SB0; LGKM8; SB0;   /* af1 ready; af2 in flight */             \
    READ_AF(af3, sA_, 3); SB0;                                                     \
    MFMA_QF(af1, 1); SB0; LGKM8; SB0;   /* af2 ready; af3 in flight */             \
    MFMA_QF(af2, 2); SB0; LGKM0; SB0;   /* af3 ready */                            \
    MFMA_QF(af3, 3);                                                               \
    if (DOS) { VM0; }                                                              \
    SB0; BARR;                                                                     \
  }

__global__ __launch_bounds__(512, 2)
void gemm1_rbf(const u16* __restrict__ Abf, const u16* __restrict__ Bbf,
               const float* __restrict__ x2, const float* __restrict__ c2,
               const float* __restrict__ beta, u16* __restrict__ Ebf,
               float* __restrict__ psum) {
  constexpr int NT = DD / 64;  // 32 K-tiles
  __shared__ __align__(16) char smem[131072];

  const int t = threadIdx.x;
  const int lane = t & 63;
  const int wave = t >> 6;
  const int wr = wave >> 2;  // 0..1: rows wr*128..
  const int wc = wave & 3;   // 0..3: cols wc*64..
  const int l15 = lane & 15;

  const int rowBase = blockIdx.y * 256;
  const int colBase = blockIdx.x * 256;

  f32x4 acc[8][4];
#pragma unroll
  for (int i = 0; i < 8; ++i)
#pragma unroll
    for (int j = 0; j < 4; ++j) acc[i][j] = 0.f;

  // staging source (pre-swizzled logical chunk)
  const int srow = t >> 3;
  const u16* gA0 = Abf + (size_t)(rowBase + srow) * DD + ((t & 7) ^ (srow & 7)) * 8;
  const u16* gB0 = Bbf + (size_t)(colBase + srow) * DD + ((t & 7) ^ (srow & 7)) * 8;

  // frag-read byte column per kstep: phys chunk = (ks*4 + l>>4) ^ (l&7)
  int cbv[2];
  cbv[0] = (((lane >> 4) & 3) ^ (lane & 7)) << 4;
  cbv[1] = ((4 + ((lane >> 4) & 3)) ^ (lane & 7)) << 4;
  const int aRow = (wr * 128 + l15) * 128;
  const int bRow = (wc * 64 + l15) * 128;

  bf16x8 bfr[4][2];
  bf16x8 af0[2][2], af1[2][2], af2[2][2], af3[2][2];

  // prologue: stage tile0 into buf0
  ST_A(0, 0, 0); ST_A(0, 1, 0); ST_B(0, 0, 0); ST_B(0, 1, 0);
  VM0;
  BARR;

#pragma unroll 2
  for (int tile = 0; tile < NT - 1; ++tile) {
    TILE_BODY(tile, tile & 1, true);
  }
  TILE_BODY(NT - 1, (NT - 1) & 1, false);

  // epilogue: C/D layout (16x16): col = lane&15, row = (lane>>4)*4 + reg
  const int khi4 = (lane >> 4) * 4;
  float* lrs = (float*)smem;  // [256 rows][stride 68] f32 partials
  float c2v[4], bet[4];
  int gc[4];
#pragma unroll
  for (int n = 0; n < 4; ++n) {
    gc[n] = colBase + wc * 64 + n * 16 + l15;
    c2v[n] = c2[gc[n]];
    bet[n] = beta[gc[n]];
  }
#pragma unroll
  for (int m = 0; m < 8; ++m) {
#pragma unroll
    for (int r = 0; r < 4; ++r) {
      const int rrel = wr * 128 + m * 16 + khi4 + r;
      const int grow = rowBase + rrel;
      const float x2v = x2[grow];
      u16* orow = Ebf + (size_t)grow * CC;
      float rs = 0.f;
#pragma unroll
      for (int n = 0; n < 4; ++n) {
        float d = acc[m][n][r];
        float sq = fmaxf(x2v + c2v[n] - 2.0f * d, 0.0f);
        float e = __expf(-bet[n] * __builtin_amdgcn_sqrtf(sq));
        rs += e;
        orow[gc[n]] = f2bf(e);
      }
      lrs[rrel * 68 + wc * 16 + l15] = rs;  // conflict-free (stride-68 pad)
    }
  }
  __syncthreads();
  if (t < 256) {
    const f32x4* p = (const f32x4*)(lrs + t * 68);  // 272B stride, 16B-aligned
    float s = 0.f;
#pragma unroll
    for (int i = 0; i < 16; ++i) {
      f32x4 v = p[i];
      s += v[0] + v[1] + v[2] + v[3];
    }
    psum[(size_t)blockIdx.x * BB + rowBase + t] = s;  // coalesced
  }
}

// ============ GEMM2: 256x128, R8 schedule; out = (E @ W^T)/rowsum + b ============
// LDS/buffer (48KB): A 256x64 bf16 (32KB) @0, B 128x64 (16KB) @32768.
// Staging: A-halves of t+1 at ph0/ph1 (other buffer), B of t+2 at ph2 (cur
// buffer, dead after ph0 reads -> guarded by ph0-end BARR); boundary vmcnt(2).
// rowsum computed in prologue from psum -> rsum_lds (fused rowsum_reduce).
// XCD-aware remap: co-locate the 8 col-blocks of one E-band per XCD.

#define ST2_A(BUF, H, TILE)                                                        \
  {                                                                                \
    const u16* _s = gA0 + (size_t)((H) * 128) * CC + (TILE) * 64;                  \
    char* _d = (char*)smem + (BUF) * 49152 + (H) * 16384 + t * 16;                 \
    __builtin_amdgcn_global_load_lds((gvp_t)_s, (lvp_t)_d, 16, 0, 0);              \
    __builtin_amdgcn_global_load_lds((gvp_t)(_s + (size_t)64 * CC),                \
                                     (lvp_t)(_d + 8192), 16, 0, 0);                \
  }

#define ST2_B(BUF, TILE)                                                           \
  {                                                                                \
    const u16* _s = gB0 + (TILE) * 64;                                             \
    char* _d = (char*)smem + (BUF) * 49152 + 32768 + t * 16;                       \
    __builtin_amdgcn_global_load_lds((gvp_t)_s, (lvp_t)_d, 16, 0, 0);              \
    __builtin_amdgcn_global_load_lds((gvp_t)(_s + (size_t)64 * CC),                \
                                     (lvp_t)(_d + 8192), 16, 0, 0);                \
  }

#define READ2_B(SBP)                                                               \
  _Pragma("unroll") for (int n_ = 0; n_ < 2; ++n_) {                               \
    _Pragma("unroll") for (int ks_ = 0; ks_ < 2; ++ks_) {                          \
      bfr[n_][ks_] = *(const bf16x8*)((SBP) + bRow + n_ * 2048 + cbv[ks_]);        \
    }                                                                              \
  }

#define READ2_A(SAP, MQ)                                                           \
  _Pragma("unroll") for (int m_ = 0; m_ < 2; ++m_) {                               \
    _Pragma("unroll") for (int ks_ = 0; ks_ < 2; ++ks_) {                          \
      af[m_][ks_] =                                                                \
          *(const bf16x8*)((SAP) + aRow + ((MQ)*2 + m_) * 2048 + cbv[ks_]);        \
    }                                                                              \
  }

#define MFMA2_Q(MQ)                                                                \
  __builtin_amdgcn_s_setprio(1);                                                   \
  _Pragma("unroll") for (int m_ = 0; m_ < 2; ++m_) {                               \
    _Pragma("unroll") for (int n_ = 0; n_ < 2; ++n_) {                             \
      _Pragma("unroll") for (int ks_ = 0; ks_ < 2; ++ks_) {                        \
        acc[(MQ)*2 + m_][n_] = __builtin_amdgcn_mfma_f32_16x16x32_bf16(            \
            af[m_][ks_], bfr[n_][ks_], acc[(MQ)*2 + m_][n_], 0, 0, 0);             \
      }                                                                            \
    }                                                                              \
  }                                                                                \
  __builtin_amdgcn_s_setprio(0)

#define TILE2_BODY(TILE, CUR, DOA, DOB, VMN)                                       \
  {                                                                                \
    const char* sA_ = (const char*)smem + (CUR) * 49152;                           \
    const char* sB_ = sA_ + 32768;                                                 \
    READ2_B(sB_);                                                                  \
    READ2_A(sA_, 0);                                                               \
    SB0;                                                                           \
    if (DOA) { ST2_A(1 - (CUR), 0, (TILE) + 1); }                                  \
    SB0; LGKM0; SB0;                                                               \
    MFMA2_Q(0); SB0; BARR;                                                         \
    READ2_A(sA_, 1); SB0;                                                          \
    if (DOA) { ST2_A(1 - (CUR), 1, (TILE) + 1); }                                  \
    SB0; LGKM0; SB0;                                                               \
    MFMA2_Q(1); SB0;                                                               \
    READ2_A(sA_, 2); SB0;                                                          \
    if (DOB) { ST2_B((CUR), (TILE) + 2); }                                         \
    SB0; LGKM0; SB0;                                                               \
    MFMA2_Q(2); SB0;                                                               \
    READ2_A(sA_, 3); SB0; LGKM0; SB0;                                              \
    MFMA2_Q(3);                                                                    \
    if ((VMN) == 2) { asm volatile("s_waitcnt vmcnt(2)" ::: "memory"); }           \
    else if ((VMN) == 0) { asm volatile("s_waitcnt vmcnt(0)" ::: "memory"); }      \
    SB0; BARR;                                                                     \
  }

__global__ __launch_bounds__(512, 2)
void gemm2_out(const u16* __restrict__ Ebf, const u16* __restrict__ Wbf,
               const float* psum, const float* __restrict__ bias,
               float* __restrict__ out) {
  constexpr int NT = CC / 64;  // 64 K-tiles
  __shared__ __align__(16) char smem[98304];
  __shared__ float rsum_lds[256];

  const int t = threadIdx.x;
  const int lane = t & 63;
  const int wave = t >> 6;
  const int wr = wave >> 2;  // 0..1: rows wr*128..
  const int wc = wave & 3;   // 0..3: cols wc*32..
  const int l15 = lane & 15;

  // XCD-aware remap (bijective on 256 blocks): dispatch d -> XCD d%8.
  const int d = blockIdx.x + (blockIdx.y << 3);
  const int s_ = d >> 3;
  const int by = (d & 7) + ((s_ >> 3) << 3);
  const int bx = s_ & 7;

  const int rowBase = by * 256;
  const int colBase = bx * 128;

  f32x4 acc[8][2];
#pragma unroll
  for (int i = 0; i < 8; ++i)
#pragma unroll
    for (int j = 0; j < 2; ++j) acc[i][j] = 0.f;

  const int srow = t >> 3;
  const u16* gA0 = Ebf + (size_t)(rowBase + srow) * CC + ((t & 7) ^ (srow & 7)) * 8;
  const u16* gB0 = Wbf + (size_t)(colBase + srow) * CC + ((t & 7) ^ (srow & 7)) * 8;

  int cbv[2];
  cbv[0] = (((lane >> 4) & 3) ^ (lane & 7)) << 4;
  cbv[1] = ((4 + ((lane >> 4) & 3)) ^ (lane & 7)) << 4;
  const int aRow = (wr * 128 + l15) * 128;
  const int bRow = (wc * 32 + l15) * 128;

  bf16x8 bfr[2][2];
  bf16x8 af[2][2];

  // fused rowsum: sum psum[0..15][row] for this block's 256 rows.
  // All 256 blocks are co-resident (1/CU); these reads complete ~60us
  // before any block's epilogue writes the aliased out region.
  float rsv = 0.f;
  if (t < 256) {
#pragma unroll
    for (int b = 0; b < 16; ++b) rsv += psum[(size_t)b * BB + rowBase + t];
  }

  // prologue: tile0 A+B complete, tile1 B in flight
  ST2_A(0, 0, 0); ST2_A(0, 1, 0); ST2_B(0, 0);
  ST2_B(1, 1);
  if (t < 256) rsum_lds[t] = rsv;
  asm volatile("s_waitcnt vmcnt(2)" ::: "memory");
  BARR;

#pragma unroll 2
  for (int tile = 0; tile < NT - 2; ++tile) {
    TILE2_BODY(tile, tile & 1, true, true, 2);
  }
  TILE2_BODY(NT - 2, (NT - 2) & 1, true, false, 0);
  TILE2_BODY(NT - 1, (NT - 1) & 1, false, false, -1);

  // epilogue
  const int khi4 = (lane >> 4) * 4;
  int gc[2];
  float bv[2];
#pragma unroll
  for (int n = 0; n < 2; ++n) {
    gc[n] = colBase + wc * 32 + n * 16 + l15;
    bv[n] = (gc[n] < KK) ? bias[gc[n]] : 0.f;
  }
#pragma unroll
  for (int m = 0; m < 8; ++m) {
#pragma unroll
    for (int r = 0; r < 4; ++r) {
      const int rrel = wr * 128 + m * 16 + khi4 + r;
      const int grow = rowBase + rrel;
      const float inv = 1.0f / rsum_lds[rrel];
#pragma unroll
      for (int n = 0; n < 2; ++n) {
        if (gc[n] < KK)
          out[(size_t)grow * KK + gc[n]] = acc[m][n][r] * inv + bv[n];
      }
    }
  }
}

// ---- workspace layout (bytes) ----
#define OFF_XB 0u                    // 8192*2048*2 = 33554432
#define OFF_CB 33554432u             // 4096*2048*2 = 16777216
#define OFF_WB 50331648u             // 1024*4096*2 = 8388608
#define OFF_EB 58720256u             // 8192*4096*2 = 67108864
#define OFF_X2 125829120u            // 8192*4
#define OFF_C2 125861888u            // 4096*4

extern "C" void kernel_launch(void* const* d_in, const int* in_sizes, int n_in,
                              void* d_out, int out_size, void* d_ws, size_t ws_size,
                              hipStream_t stream) {
  const float* x = (const float*)d_in[0];
  const float* cen = (const float*)d_in[1];
  const float* beta = (const float*)d_in[2];
  const float* W = (const float*)d_in[3];
  const float* bias = (const float*)d_in[4];
  float* out = (float*)d_out;
  char* ws = (char*)d_ws;

  u16* xb = (u16*)(ws + OFF_XB);
  u16* cb = (u16*)(ws + OFF_CB);
  u16* wb = (u16*)(ws + OFF_WB);
  u16* eb = (u16*)(ws + OFF_EB);
  float* x2 = (float*)(ws + OFF_X2);
  float* c2 = (float*)(ws + OFF_C2);
  float* psum = out;  // [16][8192] f32 = 512KB scratch in the (dead until gemm2) out buffer

  prep_all<<<BB + CC + KP, 256, 0, stream>>>(x, cen, W, xb, cb, wb, x2, c2);
  gemm1_rbf<<<dim3(CC / 256, BB / 256), 512, 0, stream>>>(xb, cb, x2, c2, beta, eb, psum);
  gemm2_out<<<dim3(KP / 128, BB / 256), 512, 0, stream>>>(eb, wb, psum, bias, out);
}

// Round 9
// 329.952 us; speedup vs baseline: 1.0374x; 1.0347x over previous
//
#include <hip/hip_runtime.h>

// ShallowRBF: x(8192x2048), centers(4096x2048), beta(4096), W(1000x4096), b(1000)
// out = (exp(-beta*||x-c||) @ W^T) / rowsum + b
//
// R12 == R11 resubmitted (previous bench failed on container acquisition, not
// the kernel): (1) gemm1 + rowsum_reduce restored to R8 exactly (best
// measured; 3 schedule variants all ~124us -> cross-wave phasing, not
// intra-wave order, is the limiter). (2) gemm2 re-tiled 4M x 2N (per-wave
// 64x64, square = LDS-traffic-optimal): 16 ds_read/wave/tile vs 20 -> -20%
// on gemm2's dominant (LDS-bound) term. Staging/swizzle/schedule unchanged.

#define BB 8192
#define DD 2048
#define CC 4096
#define KK 1000
#define KP 1024

typedef unsigned short u16;
typedef __bf16 bf16x8 __attribute__((ext_vector_type(8)));
typedef float f32x4 __attribute__((ext_vector_type(4)));

typedef const void __attribute__((address_space(1)))* gvp_t;
typedef void __attribute__((address_space(3)))* lvp_t;

__device__ __forceinline__ u16 f2bf(float f) {
  union { float f; unsigned u; } v; v.f = f;
  return (u16)((v.u + 0x7fffu + ((v.u >> 16) & 1u)) >> 16);  // RNE
}

// ---- prep (fused): row norms + bf16 casts of x, centers; W cast+pad ----
__global__ void prep_all(const float* __restrict__ x, const float* __restrict__ cen,
                         const float* __restrict__ W,
                         u16* __restrict__ xb, u16* __restrict__ cb,
                         u16* __restrict__ wb,
                         float* __restrict__ x2, float* __restrict__ c2) {
  int row = blockIdx.x;
  int t = threadIdx.x;
  if (row >= BB + CC) {  // W rows (padded to KP with zeros)
    int r = row - BB - CC;
    ushort4* dst = reinterpret_cast<ushort4*>(wb + (size_t)r * CC);
    if (r < KK) {
      const float4* src = reinterpret_cast<const float4*>(W + (size_t)r * CC);
#pragma unroll
      for (int m = 0; m < 4; ++m) {
        float4 v = src[t + 256 * m];
        dst[t + 256 * m] = make_ushort4(f2bf(v.x), f2bf(v.y), f2bf(v.z), f2bf(v.w));
      }
    } else {
#pragma unroll
      for (int m = 0; m < 4; ++m) dst[t + 256 * m] = make_ushort4(0, 0, 0, 0);
    }
    return;
  }
  const float* src;
  u16* dst;
  float* nrm;
  if (row < BB) {
    src = x + (size_t)row * DD; dst = xb + (size_t)row * DD; nrm = x2 + row;
  } else {
    int r = row - BB;
    src = cen + (size_t)r * DD; dst = cb + (size_t)r * DD; nrm = c2 + r;
  }
  float s = 0.f;
#pragma unroll
  for (int m = 0; m < 2; ++m) {
    int idx = t + 256 * m;
    float4 v = reinterpret_cast<const float4*>(src)[idx];
    s += v.x * v.x + v.y * v.y + v.z * v.z + v.w * v.w;
    reinterpret_cast<ushort4*>(dst)[idx] =
        make_ushort4(f2bf(v.x), f2bf(v.y), f2bf(v.z), f2bf(v.w));
  }
#pragma unroll
  for (int off = 1; off < 64; off <<= 1) s += __shfl_xor(s, off);
  __shared__ float red[4];
  if ((t & 63) == 0) red[t >> 6] = s;
  __syncthreads();
  if (t == 0) *nrm = red[0] + red[1] + red[2] + red[3];
}

// ======================= shared schedule helpers =======================
#define SB0 __builtin_amdgcn_sched_barrier(0)
#define BARR __builtin_amdgcn_s_barrier()
#define LGKM0 asm volatile("s_waitcnt lgkmcnt(0)" ::: "memory")

// ======================= GEMM1: 256x256, 2 barriers/tile (R8) =======================
// LDS/buffer (64KB): A 256x64 bf16 @0, B 256x64 @32768. Row=128B; logical
// chunk s of row r at phys chunk s^(r&7). Linear gload_lds dest +
// pre-swizzled global source.

#define ST_A(BUF, H, TILE)                                                         \
  {                                                                                \
    const u16* _s = gA0 + (size_t)((H) * 128) * DD + (TILE) * 64;                  \
    char* _d = (char*)smem + (BUF) * 65536 + (H) * 16384 + t * 16;                 \
    __builtin_amdgcn_global_load_lds((gvp_t)_s, (lvp_t)_d, 16, 0, 0);              \
    __builtin_amdgcn_global_load_lds((gvp_t)(_s + (size_t)64 * DD),                \
                                     (lvp_t)(_d + 8192), 16, 0, 0);                \
  }

#define ST_B(BUF, H, TILE)                                                         \
  {                                                                                \
    const u16* _s = gB0 + (size_t)((H) * 128) * DD + (TILE) * 64;                  \
    char* _d = (char*)smem + (BUF) * 65536 + 32768 + (H) * 16384 + t * 16;         \
    __builtin_amdgcn_global_load_lds((gvp_t)_s, (lvp_t)_d, 16, 0, 0);              \
    __builtin_amdgcn_global_load_lds((gvp_t)(_s + (size_t)64 * DD),                \
                                     (lvp_t)(_d + 8192), 16, 0, 0);                \
  }

#define READ_B(SBP)                                                                \
  _Pragma("unroll") for (int n_ = 0; n_ < 4; ++n_) {                               \
    _Pragma("unroll") for (int ks_ = 0; ks_ < 2; ++ks_) {                          \
      bfr[n_][ks_] = *(const bf16x8*)((SBP) + bRow + n_ * 2048 + cbv[ks_]);        \
    }                                                                              \
  }

#define READ_A(SAP, MQ)                                                            \
  _Pragma("unroll") for (int m_ = 0; m_ < 2; ++m_) {                               \
    _Pragma("unroll") for (int ks_ = 0; ks_ < 2; ++ks_) {                          \
      af[m_][ks_] =                                                                \
          *(const bf16x8*)((SAP) + aRow + ((MQ)*2 + m_) * 2048 + cbv[ks_]);        \
    }                                                                              \
  }

#define MFMA_Q(MQ)                                                                 \
  __builtin_amdgcn_s_setprio(1);                                                   \
  _Pragma("unroll") for (int m_ = 0; m_ < 2; ++m_) {                               \
    _Pragma("unroll") for (int n_ = 0; n_ < 4; ++n_) {                             \
      _Pragma("unroll") for (int ks_ = 0; ks_ < 2; ++ks_) {                        \
        acc[(MQ)*2 + m_][n_] = __builtin_amdgcn_mfma_f32_16x16x32_bf16(            \
            af[m_][ks_], bfr[n_][ks_], acc[(MQ)*2 + m_][n_], 0, 0, 0);             \
      }                                                                            \
    }                                                                              \
  }                                                                                \
  __builtin_amdgcn_s_setprio(0)

// 2 barriers per tile (R8): ph0-end BARR = all waves' B-cur reads done before
// ST_B; boundary BARR after counted vmcnt = staged data visible.
#define TILE_BODY(TILE, CUR, DOA, DOB, VMN)                                        \
  {                                                                                \
    const char* sA_ = (const char*)smem + (CUR) * 65536;                           \
    const char* sB_ = sA_ + 32768;                                                 \
    READ_B(sB_);                                                                   \
    READ_A(sA_, 0);                                                                \
    SB0;                                                                           \
    if (DOA) { ST_A(1 - (CUR), 0, (TILE) + 1); ST_A(1 - (CUR), 1, (TILE) + 1); }   \
    SB0; LGKM0; SB0;                                                               \
    MFMA_Q(0); SB0; BARR;                                                          \
    READ_A(sA_, 1); SB0;                                                           \
    if (DOB) { ST_B((CUR), 0, (TILE) + 2); }                                       \
    SB0; LGKM0; SB0;                                                               \
    MFMA_Q(1); SB0;                                                                \
    READ_A(sA_, 2); SB0;                                                           \
    if (DOB) { ST_B((CUR), 1, (TILE) + 2); }                                       \
    SB0; LGKM0; SB0;                                                               \
    MFMA_Q(2); SB0;                                                                \
    READ_A(sA_, 3); SB0; LGKM0; SB0;                                               \
    MFMA_Q(3);                                                                     \
    if ((VMN) == 4) { asm volatile("s_waitcnt vmcnt(4)" ::: "memory"); }           \
    else if ((VMN) == 0) { asm volatile("s_waitcnt vmcnt(0)" ::: "memory"); }      \
    SB0; BARR;                                                                     \
  }

__global__ __launch_bounds__(512, 2)
void gemm1_rbf(const u16* __restrict__ Abf, const u16* __restrict__ Bbf,
               const float* __restrict__ x2, const float* __restrict__ c2,
               const float* __restrict__ beta, u16* __restrict__ Ebf,
               float* __restrict__ psum) {
  constexpr int NT = DD / 64;  // 32 K-tiles
  __shared__ __align__(16) char smem[131072];

  const int t = threadIdx.x;
  const int lane = t & 63;
  const int wave = t >> 6;
  const int wr = wave >> 2;  // 0..1: rows wr*128..
  const int wc = wave & 3;   // 0..3: cols wc*64..
  const int l15 = lane & 15;

  const int rowBase = blockIdx.y * 256;
  const int colBase = blockIdx.x * 256;

  f32x4 acc[8][4];
#pragma unroll
  for (int i = 0; i < 8; ++i)
#pragma unroll
    for (int j = 0; j < 4; ++j) acc[i][j] = 0.f;

  // staging source (pre-swizzled logical chunk)
  const int srow = t >> 3;
  const u16* gA0 = Abf + (size_t)(rowBase + srow) * DD + ((t & 7) ^ (srow & 7)) * 8;
  const u16* gB0 = Bbf + (size_t)(colBase + srow) * DD + ((t & 7) ^ (srow & 7)) * 8;

  // frag-read byte column per kstep: phys chunk = (ks*4 + l>>4) ^ (l&7)
  int cbv[2];
  cbv[0] = (((lane >> 4) & 3) ^ (lane & 7)) << 4;
  cbv[1] = ((4 + ((lane >> 4) & 3)) ^ (lane & 7)) << 4;
  const int aRow = (wr * 128 + l15) * 128;
  const int bRow = (wc * 64 + l15) * 128;

  bf16x8 bfr[4][2];
  bf16x8 af[2][2];

  // prologue: tile0 complete + tile1 B-halves in flight
  ST_A(0, 0, 0); ST_A(0, 1, 0); ST_B(0, 0, 0); ST_B(0, 1, 0);
  ST_B(1, 0, 1); ST_B(1, 1, 1);
  asm volatile("s_waitcnt vmcnt(4)" ::: "memory");
  BARR;

#pragma unroll 2
  for (int tile = 0; tile < NT - 2; ++tile) {
    TILE_BODY(tile, tile & 1, true, true, 4);
  }
  TILE_BODY(NT - 2, (NT - 2) & 1, true, false, 0);
  TILE_BODY(NT - 1, (NT - 1) & 1, false, false, -1);

  // epilogue: C/D layout (16x16): col = lane&15, row = (lane>>4)*4 + reg
  const int khi4 = (lane >> 4) * 4;
  float* lrs = (float*)smem;  // [256 rows][stride 68] f32 partials
  float c2v[4], bet[4];
  int gc[4];
#pragma unroll
  for (int n = 0; n < 4; ++n) {
    gc[n] = colBase + wc * 64 + n * 16 + l15;
    c2v[n] = c2[gc[n]];
    bet[n] = beta[gc[n]];
  }
#pragma unroll
  for (int m = 0; m < 8; ++m) {
#pragma unroll
    for (int r = 0; r < 4; ++r) {
      const int rrel = wr * 128 + m * 16 + khi4 + r;
      const int grow = rowBase + rrel;
      const float x2v = x2[grow];
      u16* orow = Ebf + (size_t)grow * CC;
      float rs = 0.f;
#pragma unroll
      for (int n = 0; n < 4; ++n) {
        float d = acc[m][n][r];
        float sq = fmaxf(x2v + c2v[n] - 2.0f * d, 0.0f);
        float e = __expf(-bet[n] * __builtin_amdgcn_sqrtf(sq));
        rs += e;
        orow[gc[n]] = f2bf(e);
      }
      lrs[rrel * 68 + wc * 16 + l15] = rs;  // conflict-free (stride-68 pad)
    }
  }
  __syncthreads();
  if (t < 256) {
    const f32x4* p = (const f32x4*)(lrs + t * 68);  // 272B stride, 16B-aligned
    float s = 0.f;
#pragma unroll
    for (int i = 0; i < 16; ++i) {
      f32x4 v = p[i];
      s += v[0] + v[1] + v[2] + v[3];
    }
    psum[(size_t)blockIdx.x * BB + rowBase + t] = s;  // coalesced
  }
}

// ---- rowsum reduce: rowsum[r] = sum_b psum[b][r]  (psum is [16][8192]) ----
__global__ void rowsum_reduce(const float* __restrict__ psum, float* __restrict__ rowsum) {
  const int row = blockIdx.x * 256 + threadIdx.x;
  float s = 0.f;
#pragma unroll
  for (int b = 0; b < 16; ++b) s += psum[(size_t)b * BB + row];
  rowsum[row] = s;
}

// ============ GEMM2: 256x128, 4M x 2N waves; out = (E @ W^T)/rowsum + b ============
// LDS/buffer (48KB): A 256x64 bf16 (32KB) @0, B 128x64 (16KB) @32768.
// Per-wave 64x64 (square = LDS-traffic-optimal): B read ONCE per tile (8
// ds_read), A 2 reads per quarter -> 16 ds_read/wave/tile (was 20).
// R8 schedule: A-halves of t+1 at ph0/ph1 (other buf), B of t+2 at ph2 (cur
// buf, dead after tile-top reads, guarded by Q0-end BARR); boundary vmcnt(2).
// XCD-aware remap: co-locate the 8 col-blocks of one E-band per XCD.

#define ST2_A(BUF, H, TILE)                                                        \
  {                                                                                \
    const u16* _s = gA0 + (size_t)((H) * 128) * CC + (TILE) * 64;                  \
    char* _d = (char*)smem + (BUF) * 49152 + (H) * 16384 + t * 16;                 \
    __builtin_amdgcn_global_load_lds((gvp_t)_s, (lvp_t)_d, 16, 0, 0);              \
    __builtin_amdgcn_global_load_lds((gvp_t)(_s + (size_t)64 * CC),                \
                                     (lvp_t)(_d + 8192), 16, 0, 0);                \
  }

#define ST2_B(BUF, TILE)                                                           \
  {                                                                                \
    const u16* _s = gB0 + (TILE) * 64;                                             \
    char* _d = (char*)smem + (BUF) * 49152 + 32768 + t * 16;                       \
    __builtin_amdgcn_global_load_lds((gvp_t)_s, (lvp_t)_d, 16, 0, 0);              \
    __builtin_amdgcn_global_load_lds((gvp_t)(_s + (size_t)64 * CC),                \
                                     (lvp_t)(_d + 8192), 16, 0, 0);                \
  }

#define READ2_B(SBP)                                                               \
  _Pragma("unroll") for (int n_ = 0; n_ < 4; ++n_) {                               \
    _Pragma("unroll") for (int ks_ = 0; ks_ < 2; ++ks_) {                          \
      bfr[n_][ks_] = *(const bf16x8*)((SBP) + bRow + n_ * 2048 + cbv[ks_]);        \
    }                                                                              \
  }

#define READ2_A(SAP, MQ)                                                           \
  _Pragma("unroll") for (int ks_ = 0; ks_ < 2; ++ks_) {                            \
    af[ks_] = *(const bf16x8*)((SAP) + aRow + (MQ) * 2048 + cbv[ks_]);             \
  }

#define MFMA2_Q(MQ)                                                                \
  __builtin_amdgcn_s_setprio(1);                                                   \
  _Pragma("unroll") for (int n_ = 0; n_ < 4; ++n_) {                               \
    _Pragma("unroll") for (int ks_ = 0; ks_ < 2; ++ks_) {                          \
      acc[MQ][n_] = __builtin_amdgcn_mfma_f32_16x16x32_bf16(                       \
          af[ks_], bfr[n_][ks_], acc[MQ][n_], 0, 0, 0);                            \
    }                                                                              \
  }                                                                                \
  __builtin_amdgcn_s_setprio(0)

#define TILE2_BODY(TILE, CUR, DOA, DOB, VMN)                                       \
  {                                                                                \
    const char* sA_ = (const char*)smem + (CUR) * 49152;                           \
    const char* sB_ = sA_ + 32768;                                                 \
    READ2_B(sB_);                                                                  \
    READ2_A(sA_, 0);                                                               \
    SB0;                                                                           \
    if (DOA) { ST2_A(1 - (CUR), 0, (TILE) + 1); }                                  \
    SB0; LGKM0; SB0;                                                               \
    MFMA2_Q(0); SB0; BARR;                                                         \
    READ2_A(sA_, 1); SB0;                                                          \
    if (DOA) { ST2_A(1 - (CUR), 1, (TILE) + 1); }                                  \
    SB0; LGKM0; SB0;                                                               \
    MFMA2_Q(1); SB0;                                                               \
    READ2_A(sA_, 2); SB0;                                                          \
    if (DOB) { ST2_B((CUR), (TILE) + 2); }                                         \
    SB0; LGKM0; SB0;                                                               \
    MFMA2_Q(2); SB0;                                                               \
    READ2_A(sA_, 3); SB0; LGKM0; SB0;                                              \
    MFMA2_Q(3);                                                                    \
    if ((VMN) == 2) { asm volatile("s_waitcnt vmcnt(2)" ::: "memory"); }           \
    else if ((VMN) == 0) { asm volatile("s_waitcnt vmcnt(0)" ::: "memory"); }      \
    SB0; BARR;                                                                     \
  }

__global__ __launch_bounds__(512, 2)
void gemm2_out(const u16* __restrict__ Ebf, const u16* __restrict__ Wbf,
               const float* __restrict__ rowsum, const float* __restrict__ bias,
               float* __restrict__ out) {
  constexpr int NT = CC / 64;  // 64 K-tiles
  __shared__ __align__(16) char smem[98304];

  const int t = threadIdx.x;
  const int lane = t & 63;
  const int wave = t >> 6;
  const int wr = wave >> 1;  // 0..3: rows wr*64..
  const int wc = wave & 1;   // 0..1: cols wc*64..
  const int l15 = lane & 15;

  // XCD-aware remap (bijective on 256 blocks): dispatch d -> XCD d%8.
  const int d = blockIdx.x + (blockIdx.y << 3);
  const int s_ = d >> 3;
  const int by = (d & 7) + ((s_ >> 3) << 3);
  const int bx = s_ & 7;

  const int rowBase = by * 256;
  const int colBase = bx * 128;

  f32x4 acc[4][4];
#pragma unroll
  for (int i = 0; i < 4; ++i)
#pragma unroll
    for (int j = 0; j < 4; ++j) acc[i][j] = 0.f;

  const int srow = t >> 3;
  const u16* gA0 = Ebf + (size_t)(rowBase + srow) * CC + ((t & 7) ^ (srow & 7)) * 8;
  const u16* gB0 = Wbf + (size_t)(colBase + srow) * CC + ((t & 7) ^ (srow & 7)) * 8;

  int cbv[2];
  cbv[0] = (((lane >> 4) & 3) ^ (lane & 7)) << 4;
  cbv[1] = ((4 + ((lane >> 4) & 3)) ^ (lane & 7)) << 4;
  const int aRow = (wr * 64 + l15) * 128;
  const int bRow = (wc * 64 + l15) * 128;

  bf16x8 bfr[4][2];
  bf16x8 af[2];

  // prologue: tile0 A+B complete, tile1 B in flight
  ST2_A(0, 0, 0); ST2_A(0, 1, 0); ST2_B(0, 0);
  ST2_B(1, 1);
  asm volatile("s_waitcnt vmcnt(2)" ::: "memory");
  BARR;

#pragma unroll 2
  for (int tile = 0; tile < NT - 2; ++tile) {
    TILE2_BODY(tile, tile & 1, true, true, 2);
  }
  TILE2_BODY(NT - 2, (NT - 2) & 1, true, false, 0);
  TILE2_BODY(NT - 1, (NT - 1) & 1, false, false, -1);

  // epilogue: row = rowBase + wr*64 + m*16 + khi4 + r; col = colBase + wc*64 + n*16 + l15
  const int khi4 = (lane >> 4) * 4;
  int gc[4];
  float bv[4];
#pragma unroll
  for (int n = 0; n < 4; ++n) {
    gc[n] = colBase + wc * 64 + n * 16 + l15;
    bv[n] = (gc[n] < KK) ? bias[gc[n]] : 0.f;
  }
#pragma unroll
  for (int m = 0; m < 4; ++m) {
#pragma unroll
    for (int r = 0; r < 4; ++r) {
      const int grow = rowBase + wr * 64 + m * 16 + khi4 + r;
      const float inv = 1.0f / rowsum[grow];
#pragma unroll
      for (int n = 0; n < 4; ++n) {
        if (gc[n] < KK)
          out[(size_t)grow * KK + gc[n]] = acc[m][n][r] * inv + bv[n];
      }
    }
  }
}

// ---- workspace layout (bytes) ----
#define OFF_XB 0u                    // 8192*2048*2 = 33554432
#define OFF_CB 33554432u             // 4096*2048*2 = 16777216
#define OFF_WB 50331648u             // 1024*4096*2 = 8388608
#define OFF_EB 58720256u             // 8192*4096*2 = 67108864
#define OFF_X2 125829120u            // 8192*4
#define OFF_C2 125861888u            // 4096*4
#define OFF_RS 125878272u            // 8192*4

extern "C" void kernel_launch(void* const* d_in, const int* in_sizes, int n_in,
                              void* d_out, int out_size, void* d_ws, size_t ws_size,
                              hipStream_t stream) {
  const float* x = (const float*)d_in[0];
  const float* cen = (const float*)d_in[1];
  const float* beta = (const float*)d_in[2];
  const float* W = (const float*)d_in[3];
  const float* bias = (const float*)d_in[4];
  float* out = (float*)d_out;
  char* ws = (char*)d_ws;

  u16* xb = (u16*)(ws + OFF_XB);
  u16* cb = (u16*)(ws + OFF_CB);
  u16* wb = (u16*)(ws + OFF_WB);
  u16* eb = (u16*)(ws + OFF_EB);
  float* x2 = (float*)(ws + OFF_X2);
  float* c2 = (float*)(ws + OFF_C2);
  float* rowsum = (float*)(ws + OFF_RS);
  float* psum = out;  // [16][8192] f32 = 512KB scratch in the (dead until gemm2) out buffer

  prep_all<<<BB + CC + KP, 256, 0, stream>>>(x, cen, W, xb, cb, wb, x2, c2);
  gemm1_rbf<<<dim3(CC / 256, BB / 256), 512, 0, stream>>>(xb, cb, x2, c2, beta, eb, psum);
  rowsum_reduce<<<BB / 256, 256, 0, stream>>>(psum, rowsum);
  gemm2_out<<<dim3(KP / 128, BB / 256), 512, 0, stream>>>(eb, wb, rowsum, bias, out);
}